// Round 1
// baseline (12465.942 us; speedup 1.0000x reference)
//
#include <hip/hip_runtime.h>
#include <hip/hip_bf16.h>

// ============================================================================
// xLSTM audio model, fp32 correctness-first implementation.
// B=4, S=1024, D=1024, INNER=2048, NH_M=4, DH_M=512, NH_S=4, DH_S=256,
// K(conv)=4, FF_UP=1344. N = B*S = 4096 tokens.
//
// Workspace layout (float offsets). Total need ~41.1M floats = ~165 MB.
//   OFF_XN  0        4M   xn / xn2 / ffn-ln / ln+selu tmp
//   OFF_UP  4M      16M   up(xi|z, v in-place over xi) -> gate preacts i,f,z,o -> ffn g|u
//   OFF_XC  20M      8M   xc (block0) -> xc2 (4M) + hs (4M at 24M)
//   OFF_H   28M      8M   mLSTM h (B,S,NH,DH) -> gated in-place -> x2 (4M)
//   OFF_X1  36M      4M   x1 / x3
//   OFF_SM  40M     <1M   fused Wig/Wfg (4x8192), ig/fg (2x16384), lfc (16384), feat(4096)
// ============================================================================

#define DEV_INLINE __device__ __forceinline__

constexpr long OFF_XN = 0;
constexpr long OFF_UP = 4l << 20;
constexpr long OFF_XC = 20l << 20;
constexpr long OFF_HS = 24l << 20;
constexpr long OFF_H  = 28l << 20;
constexpr long OFF_X1 = 36l << 20;
constexpr long OFF_SM = 40l << 20;

DEV_INLINE float wave_reduce_sum(float v) {
#pragma unroll
  for (int o = 32; o > 0; o >>= 1) v += __shfl_xor(v, o);
  return v;
}

DEV_INLINE float silu_f(float x) { return x / (1.f + expf(-x)); }
DEV_INLINE float selu_f(float x) {
  return 1.0507009873554805f * (x > 0.f ? x : 1.6732632423543772f * (expf(x) - 1.f));
}

// ---------------------------------------------------------------------------
// LayerNorm over D=1024 (one row per block, 256 threads), optional SELU.
// ---------------------------------------------------------------------------
__global__ __launch_bounds__(256) void ln1024_kernel(
    const float* __restrict__ in, const float* __restrict__ w,
    float* __restrict__ out, int applySelu) {
  __shared__ float sred[8];
  const int n = blockIdx.x, t = threadIdx.x;
  const long base = (long)n * 1024 + t * 4;
  float4 v = *(const float4*)&in[base];
  float s = v.x + v.y + v.z + v.w;
  s = wave_reduce_sum(s);
  const int wid = t >> 6;
  if ((t & 63) == 0) sred[wid] = s;
  __syncthreads();
  const float mu = (sred[0] + sred[1] + sred[2] + sred[3]) * (1.f / 1024.f);
  float4 d;
  d.x = v.x - mu; d.y = v.y - mu; d.z = v.z - mu; d.w = v.w - mu;
  float sq = d.x * d.x + d.y * d.y + d.z * d.z + d.w * d.w;
  sq = wave_reduce_sum(sq);
  if ((t & 63) == 0) sred[4 + wid] = sq;
  __syncthreads();
  const float var = (sred[4] + sred[5] + sred[6] + sred[7]) * (1.f / 1024.f);
  const float rstd = rsqrtf(var + 1e-5f);
  const float4 w4 = *(const float4*)&w[t * 4];
  float4 o4;
  o4.x = d.x * rstd * w4.x; o4.y = d.y * rstd * w4.y;
  o4.z = d.z * rstd * w4.z; o4.w = d.w * rstd * w4.w;
  if (applySelu) {
    o4.x = selu_f(o4.x); o4.y = selu_f(o4.y); o4.z = selu_f(o4.z); o4.w = selu_f(o4.w);
  }
  *(float4*)&out[base] = o4;
}

// ---------------------------------------------------------------------------
// Tiled SGEMM: C[m,n] = sum_k A[m,k]*B[k,n] (+ Res). 128x128x8 tile, 256 thr,
// 8x8 micro-tile. WT=false: W is (K,N) row-major. WT=true: W is (N,K).
// blockIdx.z batches heads via aZ/wZ/cZ element offsets.
// ---------------------------------------------------------------------------
template <bool WT>
__global__ __launch_bounds__(256) void gemm_kernel(
    const float* __restrict__ A, int lda, long aZ,
    const float* __restrict__ W, int ldw, long wZ,
    const float* __restrict__ Res, int ldr, long rZ,
    float* __restrict__ C, int ldc, long cZ,
    int M, int N, int Kd) {
  __shared__ float As[8][128];
  __shared__ float Bs[8][132];
  const int bn = blockIdx.x * 128;
  const int bm = blockIdx.y * 128;
  A += (long)blockIdx.z * aZ;
  W += (long)blockIdx.z * wZ;
  C += (long)blockIdx.z * cZ;
  const float* Rp = Res ? Res + (long)blockIdx.z * rZ : nullptr;
  const int t = threadIdx.x;
  const int tx = t & 15, ty = t >> 4;

  float acc[8][8] = {};

  const int ar = t >> 1, ak = (t & 1) * 4;
  for (int k0 = 0; k0 < Kd; k0 += 8) {
    const float4 av = *(const float4*)&A[(long)(bm + ar) * lda + k0 + ak];
    float4 bv;
    int bk, bn4, bnr, bk4;
    if (!WT) {
      bk = t >> 5; bn4 = (t & 31) << 2;
      bv = *(const float4*)&W[(long)(k0 + bk) * ldw + bn + bn4];
    } else {
      bnr = t >> 1; bk4 = (t & 1) * 4;
      bv = *(const float4*)&W[(long)(bn + bnr) * ldw + k0 + bk4];
    }
    As[ak + 0][ar] = av.x; As[ak + 1][ar] = av.y;
    As[ak + 2][ar] = av.z; As[ak + 3][ar] = av.w;
    if (!WT) {
      *(float4*)&Bs[bk][bn4] = bv;
    } else {
      Bs[bk4 + 0][bnr] = bv.x; Bs[bk4 + 1][bnr] = bv.y;
      Bs[bk4 + 2][bnr] = bv.z; Bs[bk4 + 3][bnr] = bv.w;
    }
    __syncthreads();
#pragma unroll
    for (int kk = 0; kk < 8; ++kk) {
      float a0[8], b0[8];
      *(float4*)&a0[0] = *(const float4*)&As[kk][ty * 8];
      *(float4*)&a0[4] = *(const float4*)&As[kk][ty * 8 + 4];
      *(float4*)&b0[0] = *(const float4*)&Bs[kk][tx * 8];
      *(float4*)&b0[4] = *(const float4*)&Bs[kk][tx * 8 + 4];
#pragma unroll
      for (int i = 0; i < 8; ++i)
#pragma unroll
        for (int j = 0; j < 8; ++j) acc[i][j] += a0[i] * b0[j];
    }
    __syncthreads();
  }

  const int row0 = bm + ty * 8, col0 = bn + tx * 8;
#pragma unroll
  for (int i = 0; i < 8; ++i) {
#pragma unroll
    for (int jq = 0; jq < 8; jq += 4) {
      float4 o;
      o.x = acc[i][jq + 0]; o.y = acc[i][jq + 1];
      o.z = acc[i][jq + 2]; o.w = acc[i][jq + 3];
      if (Rp) {
        const float4 r4 = *(const float4*)&Rp[(long)(row0 + i) * ldr + col0 + jq];
        o.x += r4.x; o.y += r4.y; o.z += r4.z; o.w += r4.w;
      }
      *(float4*)&C[(long)(row0 + i) * ldc + col0 + jq] = o;
    }
  }
}

// ---------------------------------------------------------------------------
// Depthwise causal conv1d (K=4) + SiLU. One float4 channel-group per thread.
// ---------------------------------------------------------------------------
__global__ __launch_bounds__(256) void conv_silu_kernel(
    const float* __restrict__ in, int ld_in,
    const float* __restrict__ w, const float* __restrict__ bias,
    float* __restrict__ out, int ld_out, int C) {
  const int idx = blockIdx.x * 256 + threadIdx.x;
  const int gpr = C >> 2;
  const int n = idx / gpr;
  const int c = (idx - n * gpr) << 2;
  const int s = n & 1023;
  float4 acc = *(const float4*)&bias[c];
  const float* wc = &w[c * 4];
#pragma unroll
  for (int tap = 0; tap < 4; ++tap) {
    const int sp = s - 3 + tap;
    if (sp >= 0) {
      const float4 xv = *(const float4*)&in[(long)(n - 3 + tap) * ld_in + c];
      acc.x += xv.x * wc[0 + tap];
      acc.y += xv.y * wc[4 + tap];
      acc.z += xv.z * wc[8 + tap];
      acc.w += xv.w * wc[12 + tap];
    }
  }
  acc.x = silu_f(acc.x); acc.y = silu_f(acc.y);
  acc.z = silu_f(acc.z); acc.w = silu_f(acc.w);
  *(float4*)&out[(long)n * ld_out + c] = acc;
}

// ---------------------------------------------------------------------------
// Fold the 4x4 block-diagonal q/k/v maps into Wig/Wfg:
//   Wt[c,h] = sum_o Wblk[c/4, o, c%4] * Wg[base + 4*(c/4) + o, h]
// Outputs (2048 x 4) each: wqk_* = q-part + k-part (applied to xc), wv_* (to xi).
// ---------------------------------------------------------------------------
__global__ __launch_bounds__(256) void wtilde_kernel(
    const float* __restrict__ Wq, const float* __restrict__ Wk,
    const float* __restrict__ Wv, const float* __restrict__ Wig,
    const float* __restrict__ Wfg,
    float* __restrict__ wqk_ig, float* __restrict__ wv_ig,
    float* __restrict__ wqk_fg, float* __restrict__ wv_fg) {
  const int idx = blockIdx.x * 256 + threadIdx.x;  // 8192
  const int c = idx >> 2, hm = idx & 3;
  const int bk = c >> 2, i = c & 3;
  float sqk_i = 0, sv_i = 0, sqk_f = 0, sv_f = 0;
#pragma unroll
  for (int o = 0; o < 4; ++o) {
    const float wq = Wq[(bk * 4 + o) * 4 + i];
    const float wk = Wk[(bk * 4 + o) * 4 + i];
    const float wv = Wv[(bk * 4 + o) * 4 + i];
    const int rq = bk * 4 + o;
    sqk_i += wq * Wig[rq * 4 + hm] + wk * Wig[(2048 + rq) * 4 + hm];
    sv_i  += wv * Wig[(4096 + rq) * 4 + hm];
    sqk_f += wq * Wfg[rq * 4 + hm] + wk * Wfg[(2048 + rq) * 4 + hm];
    sv_f  += wv * Wfg[(4096 + rq) * 4 + hm];
  }
  wqk_ig[idx] = sqk_i; wv_ig[idx] = sv_i;
  wqk_fg[idx] = sqk_f; wv_fg[idx] = sv_f;
}

// ---------------------------------------------------------------------------
// ig/fg: per token, 8 dot products of length 4096 (xc part + xi part).
// Writes ig/fg in (B, NH, S) layout.
// ---------------------------------------------------------------------------
__global__ __launch_bounds__(256) void igfg_kernel(
    const float* __restrict__ xc, const float* __restrict__ up,
    const float* __restrict__ wqk_ig, const float* __restrict__ wv_ig,
    const float* __restrict__ wqk_fg, const float* __restrict__ wv_fg,
    const float* __restrict__ big, const float* __restrict__ bfg,
    float* __restrict__ ig, float* __restrict__ fg) {
  __shared__ float red[4][8];
  const int n = blockIdx.x, t = threadIdx.x;
  float ai[4] = {0, 0, 0, 0}, af[4] = {0, 0, 0, 0};
  for (int c = t; c < 2048; c += 256) {
    const float xcv = xc[(long)n * 2048 + c];
    const float xiv = up[(long)n * 4096 + c];
    const float4 wiq = *(const float4*)&wqk_ig[c * 4];
    const float4 wiv = *(const float4*)&wv_ig[c * 4];
    const float4 wfq = *(const float4*)&wqk_fg[c * 4];
    const float4 wfv = *(const float4*)&wv_fg[c * 4];
    ai[0] += xcv * wiq.x + xiv * wiv.x;
    ai[1] += xcv * wiq.y + xiv * wiv.y;
    ai[2] += xcv * wiq.z + xiv * wiv.z;
    ai[3] += xcv * wiq.w + xiv * wiv.w;
    af[0] += xcv * wfq.x + xiv * wfv.x;
    af[1] += xcv * wfq.y + xiv * wfv.y;
    af[2] += xcv * wfq.z + xiv * wfv.z;
    af[3] += xcv * wfq.w + xiv * wfv.w;
  }
#pragma unroll
  for (int j = 0; j < 4; ++j) {
    ai[j] = wave_reduce_sum(ai[j]);
    af[j] = wave_reduce_sum(af[j]);
  }
  const int wid = t >> 6;
  if ((t & 63) == 0) {
#pragma unroll
    for (int j = 0; j < 4; ++j) { red[wid][j] = ai[j]; red[wid][4 + j] = af[j]; }
  }
  __syncthreads();
  if (t < 8) {
    const float v = red[0][t] + red[1][t] + red[2][t] + red[3][t];
    const int b = n >> 10, s = n & 1023;
    if (t < 4) ig[((long)b * 4 + t) * 1024 + s] = v + big[t];
    else       fg[((long)b * 4 + (t - 4)) * 1024 + s] = v + bfg[t - 4];
  }
}

// ---------------------------------------------------------------------------
// lfc = cumsum(log_sigmoid(fg)) over S per (b,h). Hillis-Steele in LDS.
// ---------------------------------------------------------------------------
__global__ __launch_bounds__(1024) void lfc_kernel(
    const float* __restrict__ fg, float* __restrict__ lfc) {
  __shared__ float sh[1024];
  const int bh = blockIdx.x, t = threadIdx.x;
  const float x = fg[(long)bh * 1024 + t];
  sh[t] = fminf(x, 0.f) - log1pf(expf(-fabsf(x)));
  __syncthreads();
  for (int off = 1; off < 1024; off <<= 1) {
    const float add = (t >= off) ? sh[t - off] : 0.f;
    __syncthreads();
    sh[t] += add;
    __syncthreads();
  }
  lfc[(long)bh * 1024 + t] = sh[t];
}

// ---------------------------------------------------------------------------
// v = headwise(xi, Wv) in place over the xi region of `up`.
// ---------------------------------------------------------------------------
__global__ __launch_bounds__(256) void hv_inplace_kernel(
    float* __restrict__ up, const float* __restrict__ Wv) {
  const int idx = blockIdx.x * 256 + threadIdx.x;  // Ntok*512
  const int n = idx >> 9, bk = idx & 511;
  const long a = (long)n * 4096 + (bk << 2);
  const float4 xv = *(const float4*)&up[a];
  const float* wb = &Wv[bk << 4];
  float4 o;
  o.x = xv.x * wb[0]  + xv.y * wb[1]  + xv.z * wb[2]  + xv.w * wb[3];
  o.y = xv.x * wb[4]  + xv.y * wb[5]  + xv.z * wb[6]  + xv.w * wb[7];
  o.z = xv.x * wb[8]  + xv.y * wb[9]  + xv.z * wb[10] + xv.w * wb[11];
  o.w = xv.x * wb[12] + xv.y * wb[13] + xv.z * wb[14] + xv.w * wb[15];
  *(float4*)&up[a] = o;
}

// ---------------------------------------------------------------------------
// mLSTM parallel, flash-style. Grid (32 rowblocks, 16 bh), 256 threads.
// q,k recomputed on-the-fly from xc; v read from up (in-place transformed).
// Thread (ti in [0,8), tj in [0,32)): rows 4*ti+e, qk col tj, pv d = tj+32u.
// ---------------------------------------------------------------------------
__global__ __launch_bounds__(256) void mlstm_attn_kernel(
    const float* __restrict__ xc, const float* __restrict__ up,
    const float* __restrict__ Wq, const float* __restrict__ Wk,
    const float* __restrict__ lfc, const float* __restrict__ igv,
    float* __restrict__ hout) {
  __shared__ float q_s[32][516];
  __shared__ float kv_s[32][516];
  __shared__ float p_s[32][36];
  __shared__ float lfci_s[32], lfcj_s[32], igj_s[32];
  const int t = threadIdx.x;
  const int ti = t >> 5, tj = t & 31;
  const int i0 = blockIdx.x * 32;
  const int bh = blockIdx.y;
  const int b = bh >> 2, h = bh & 3;
  const float kscale = 0.04419417382415922f;  // 512^-0.5

  // q tile (compute from xc)
  for (int idx = t; idx < 32 * 128; idx += 256) {
    const int r = idx >> 7, g = idx & 127;
    const float4 xv =
        *(const float4*)&xc[((long)(b * 1024 + i0 + r)) * 2048 + h * 512 + (g << 2)];
    const float* wb = Wq + ((h * 128 + g) << 4);
    float4 q4;
    q4.x = xv.x * wb[0]  + xv.y * wb[1]  + xv.z * wb[2]  + xv.w * wb[3];
    q4.y = xv.x * wb[4]  + xv.y * wb[5]  + xv.z * wb[6]  + xv.w * wb[7];
    q4.z = xv.x * wb[8]  + xv.y * wb[9]  + xv.z * wb[10] + xv.w * wb[11];
    q4.w = xv.x * wb[12] + xv.y * wb[13] + xv.z * wb[14] + xv.w * wb[15];
    *(float4*)&q_s[r][g << 2] = q4;
  }
  if (t < 32) lfci_s[t] = lfc[(long)bh * 1024 + i0 + t];

  const int r0 = ti * 4;
  float m_run[4], ssum[4], accv[4][16];
#pragma unroll
  for (int e = 0; e < 4; ++e) {
    m_run[e] = -INFINITY; ssum[e] = 0.f;
#pragma unroll
    for (int u = 0; u < 16; ++u) accv[e][u] = 0.f;
  }

  for (int j0 = 0; j0 <= i0; j0 += 32) {
    __syncthreads();  // kv_s reuse from previous pv
    // k tile (compute from xc, fold 1/sqrt(DH))
    for (int idx = t; idx < 32 * 128; idx += 256) {
      const int r = idx >> 7, g = idx & 127;
      const float4 xv =
          *(const float4*)&xc[((long)(b * 1024 + j0 + r)) * 2048 + h * 512 + (g << 2)];
      const float* wb = Wk + ((h * 128 + g) << 4);
      float4 k4;
      k4.x = (xv.x * wb[0]  + xv.y * wb[1]  + xv.z * wb[2]  + xv.w * wb[3])  * kscale;
      k4.y = (xv.x * wb[4]  + xv.y * wb[5]  + xv.z * wb[6]  + xv.w * wb[7])  * kscale;
      k4.z = (xv.x * wb[8]  + xv.y * wb[9]  + xv.z * wb[10] + xv.w * wb[11]) * kscale;
      k4.w = (xv.x * wb[12] + xv.y * wb[13] + xv.z * wb[14] + xv.w * wb[15]) * kscale;
      *(float4*)&kv_s[r][g << 2] = k4;
    }
    if (t < 32) {
      lfcj_s[t] = lfc[(long)bh * 1024 + j0 + t];
      igj_s[t] = igv[(long)bh * 1024 + j0 + t];
    }
    __syncthreads();

    // qk: 4 rows x 1 col per thread
    float sv[4] = {0.f, 0.f, 0.f, 0.f};
#pragma unroll 2
    for (int d = 0; d < 512; d += 4) {
      const float4 kv = *(const float4*)&kv_s[tj][d];
#pragma unroll
      for (int e = 0; e < 4; ++e) {
        const float4 qv = *(const float4*)&q_s[r0 + e][d];
        sv[e] += qv.x * kv.x + qv.y * kv.y + qv.z * kv.z + qv.w * kv.w;
      }
    }
    const float lfcj = lfcj_s[tj], igj = igj_s[tj];
    float mt[4], logd[4];
    bool valid[4];
#pragma unroll
    for (int e = 0; e < 4; ++e) {
      valid[e] = (j0 + tj) <= (i0 + r0 + e);
      logd[e] = lfci_s[r0 + e] - lfcj + igj;
      mt[e] = valid[e] ? logd[e] : -INFINITY;
    }
#pragma unroll
    for (int o = 16; o > 0; o >>= 1) {
#pragma unroll
      for (int e = 0; e < 4; ++e) mt[e] = fmaxf(mt[e], __shfl_xor(mt[e], o));
    }
    float p[4];
#pragma unroll
    for (int e = 0; e < 4; ++e) {
      const float mn = fmaxf(m_run[e], mt[e]);
      const float scale = __expf(m_run[e] - mn);
      m_run[e] = mn;
      p[e] = valid[e] ? sv[e] * __expf(logd[e] - mn) : 0.f;
      float ps = p[e];
#pragma unroll
      for (int o = 16; o > 0; o >>= 1) ps += __shfl_xor(ps, o);
      ssum[e] = ssum[e] * scale + ps;
#pragma unroll
      for (int u = 0; u < 16; ++u) accv[e][u] *= scale;
      p_s[r0 + e][tj] = p[e];
    }
    __syncthreads();

    // v tile (precomputed, plain copy)
    for (int idx = t; idx < 32 * 128; idx += 256) {
      const int r = idx >> 7, g = idx & 127;
      const float4 vv =
          *(const float4*)&up[((long)(b * 1024 + j0 + r)) * 4096 + h * 512 + (g << 2)];
      *(float4*)&kv_s[r][g << 2] = vv;
    }
    __syncthreads();

    // pv
#pragma unroll 2
    for (int j = 0; j < 32; ++j) {
      const float pj0 = p_s[r0 + 0][j];
      const float pj1 = p_s[r0 + 1][j];
      const float pj2 = p_s[r0 + 2][j];
      const float pj3 = p_s[r0 + 3][j];
#pragma unroll
      for (int u = 0; u < 16; ++u) {
        const float vv = kv_s[j][tj + (u << 5)];
        accv[0][u] += pj0 * vv;
        accv[1][u] += pj1 * vv;
        accv[2][u] += pj2 * vv;
        accv[3][u] += pj3 * vv;
      }
    }
  }

#pragma unroll
  for (int e = 0; e < 4; ++e) {
    const float norm = fmaxf(fabsf(ssum[e]), __expf(-m_run[e]));
    const float inv = 1.f / (norm + 1e-6f);
    const long rowbase = ((long)(b * 1024 + i0 + r0 + e)) * 2048 + h * 512;
#pragma unroll
    for (int u = 0; u < 16; ++u) hout[rowbase + tj + (u << 5)] = accv[e][u] * inv;
  }
}

// ---------------------------------------------------------------------------
// Block-0 epilogue: per-head LN of h (DH=512), then (hn + skip*xc)*silu(z),
// in place over h. One (n, head) per block of 128 threads.
// ---------------------------------------------------------------------------
__global__ __launch_bounds__(128) void mhgate_kernel(
    float* __restrict__ hbuf, const float* __restrict__ mhw,
    const float* __restrict__ skip, const float* __restrict__ xc,
    const float* __restrict__ up) {
  __shared__ float sred[4];
  const int nh = blockIdx.x, t = threadIdx.x;
  const int n = nh >> 2, hd = nh & 3;
  const long base = (long)n * 2048 + hd * 512 + t * 4;
  const float4 v = *(const float4*)&hbuf[base];
  float s = wave_reduce_sum(v.x + v.y + v.z + v.w);
  if ((t & 63) == 0) sred[t >> 6] = s;
  __syncthreads();
  const float mu = (sred[0] + sred[1]) * (1.f / 512.f);
  float4 d;
  d.x = v.x - mu; d.y = v.y - mu; d.z = v.z - mu; d.w = v.w - mu;
  float sq = wave_reduce_sum(d.x * d.x + d.y * d.y + d.z * d.z + d.w * d.w);
  if ((t & 63) == 0) sred[2 + (t >> 6)] = sq;
  __syncthreads();
  const float rstd = rsqrtf((sred[2] + sred[3]) * (1.f / 512.f) + 1e-5f);
  const int ch = hd * 512 + t * 4;
  const float4 w4 = *(const float4*)&mhw[ch];
  const float4 sk4 = *(const float4*)&skip[ch];
  const float4 xc4 = *(const float4*)&xc[(long)n * 2048 + ch];
  const float4 z4 = *(const float4*)&up[(long)n * 4096 + 2048 + ch];
  float4 o;
  o.x = (d.x * rstd * w4.x + sk4.x * xc4.x) * silu_f(z4.x);
  o.y = (d.y * rstd * w4.y + sk4.y * xc4.y) * silu_f(z4.y);
  o.z = (d.z * rstd * w4.z + sk4.z * xc4.z) * silu_f(z4.z);
  o.w = (d.w * rstd * w4.w + sk4.w * xc4.w) * silu_f(z4.w);
  *(float4*)&hbuf[base] = o;
}

// ---------------------------------------------------------------------------
// sLSTM sequential scan. One block (1024 threads) per (b,h).
// Thread k owns recurrent column k; threads <256 own channel state.
// ---------------------------------------------------------------------------
__global__ __launch_bounds__(1024) void slstm_scan_kernel(
    const float* __restrict__ gi, const float* __restrict__ gf,
    const float* __restrict__ gz, const float* __restrict__ go,
    const float* __restrict__ R, const float* __restrict__ bias,
    float* __restrict__ hsout) {
  __shared__ float h_cur[256];
  __shared__ float ry[1024];
  const int t = threadIdx.x;
  const int b = blockIdx.x >> 2, hd = blockIdx.x & 3;
  const float* Rc = R + (long)hd * (256 * 1024) + t;
  float c = 0.f, nn = 0.f, m = 0.f;
  float bi = 0, bf = 0, bz = 0, bo = 0;
  if (t < 256) {
    h_cur[t] = 0.f;
    bi = bias[(hd * 4 + 0) * 256 + t];
    bf = bias[(hd * 4 + 1) * 256 + t];
    bz = bias[(hd * 4 + 2) * 256 + t];
    bo = bias[(hd * 4 + 3) * 256 + t];
  }
  __syncthreads();
  for (int s = 0; s < 1024; ++s) {
    float acc = 0.f;
#pragma unroll 8
    for (int d = 0; d < 256; d += 4) {
      const float4 hv = *(const float4*)&h_cur[d];
      const float r0 = Rc[(long)(d + 0) * 1024];
      const float r1 = Rc[(long)(d + 1) * 1024];
      const float r2 = Rc[(long)(d + 2) * 1024];
      const float r3 = Rc[(long)(d + 3) * 1024];
      acc += hv.x * r0 + hv.y * r1 + hv.z * r2 + hv.w * r3;
    }
    ry[t] = acc;
    __syncthreads();
    if (t < 256) {
      const long pb = ((long)(b * 1024 + s)) * 1024 + hd * 256 + t;
      const float ir = gi[pb] + ry[t] + bi;
      const float fr = gf[pb] + ry[256 + t] + bf;
      const float zr = gz[pb] + ry[512 + t] + bz;
      const float og = go[pb] + ry[768 + t] + bo;
      const float lsf = fminf(fr, 0.f) - log1pf(expf(-fabsf(fr)));
      const float lfm = m + lsf;
      const float mn = fmaxf(ir, lfm);
      const float igate = expf(ir - mn);
      const float fgate = expf(lfm - mn);
      c = fgate * c + igate * tanhf(zr);
      nn = fgate * nn + igate;
      const float hv = (1.f / (1.f + expf(-og))) * (c / (nn + 1e-6f));
      m = mn;
      h_cur[t] = hv;
      hsout[pb] = hv;
    }
    __syncthreads();
  }
}

// ---------------------------------------------------------------------------
// sLSTM epilogue: x2 = x1 + mh_layernorm(hs) * w. One (n,head) per 64-thr block.
// ---------------------------------------------------------------------------
__global__ __launch_bounds__(64) void mhres_kernel(
    const float* __restrict__ hs, const float* __restrict__ w,
    const float* __restrict__ x1, float* __restrict__ x2) {
  const int nh = blockIdx.x, t = threadIdx.x;
  const int n = nh >> 2, hd = nh & 3;
  const long base = (long)n * 1024 + hd * 256 + t * 4;
  const float4 v = *(const float4*)&hs[base];
  const float mu = wave_reduce_sum(v.x + v.y + v.z + v.w) * (1.f / 256.f);
  float4 d;
  d.x = v.x - mu; d.y = v.y - mu; d.z = v.z - mu; d.w = v.w - mu;
  const float var =
      wave_reduce_sum(d.x * d.x + d.y * d.y + d.z * d.z + d.w * d.w) * (1.f / 256.f);
  const float rstd = rsqrtf(var + 1e-5f);
  const float4 w4 = *(const float4*)&w[hd * 256 + t * 4];
  const float4 r4 = *(const float4*)&x1[base];
  float4 o;
  o.x = r4.x + d.x * rstd * w4.x;
  o.y = r4.y + d.y * rstd * w4.y;
  o.z = r4.z + d.z * rstd * w4.z;
  o.w = r4.w + d.w * rstd * w4.w;
  *(float4*)&x2[base] = o;
}

// ---------------------------------------------------------------------------
// GeGLU (tanh-approx gelu, matching jax.nn.gelu default), in place over g.
// ---------------------------------------------------------------------------
__global__ __launch_bounds__(256) void geglu_kernel(float* __restrict__ ffn) {
  const int idx = blockIdx.x * 256 + threadIdx.x;
  const int n = idx / 1344, j = idx % 1344;
  const long base = (long)n * 2688;
  const float g = ffn[base + j];
  const float u = ffn[base + 1344 + j];
  const float t3 = 0.7978845608028654f * (g + 0.044715f * g * g * g);
  ffn[base + j] = 0.5f * g * (1.f + tanhf(t3)) * u;
}

// ---------------------------------------------------------------------------
// Column mean over S: feat[b,d] = mean_s tmp[b,s,d].
// ---------------------------------------------------------------------------
__global__ __launch_bounds__(256) void colmean_kernel(
    const float* __restrict__ tmp, float* __restrict__ feat) {
  const int b = blockIdx.x >> 2;
  const int ch = ((blockIdx.x & 3) << 8) + threadIdx.x;
  const float* p = tmp + (long)b * 1024 * 1024 + ch;
  float s = 0.f;
#pragma unroll 4
  for (int si = 0; si < 1024; ++si) s += p[(long)si * 1024];
  feat[b * 1024 + ch] = s * (1.f / 1024.f);
}

// ---------------------------------------------------------------------------
// Classification heads: out[b, 0:7] = feat@We+be, out[b, 7:10] = feat@Ws+bs.
// ---------------------------------------------------------------------------
__global__ __launch_bounds__(256) void head_kernel(
    const float* __restrict__ feat, const float* __restrict__ We,
    const float* __restrict__ be, const float* __restrict__ Ws,
    const float* __restrict__ bs, float* __restrict__ out) {
  __shared__ float sred[4];
  const int o = blockIdx.x, t = threadIdx.x;
  const int b = o / 10, j = o % 10;
  const float* wcol;
  int ld;
  float bias;
  if (j < 7) { wcol = We + j; ld = 7; bias = be[j]; }
  else       { wcol = Ws + (j - 7); ld = 3; bias = bs[j - 7]; }
  float s = 0.f;
  for (int d = t; d < 1024; d += 256) s += feat[b * 1024 + d] * wcol[d * ld];
  s = wave_reduce_sum(s);
  if ((t & 63) == 0) sred[t >> 6] = s;
  __syncthreads();
  if (t == 0) out[o] = sred[0] + sred[1] + sred[2] + sred[3] + bias;
}

// ===========================================================================
extern "C" void kernel_launch(void* const* d_in, const int* in_sizes, int n_in,
                              void* d_out, int out_size, void* d_ws, size_t ws_size,
                              hipStream_t stream) {
  (void)in_sizes; (void)n_in; (void)out_size; (void)ws_size;
  const float* x        = (const float*)d_in[0];
  const float* m_ln_w   = (const float*)d_in[1];
  const float* m_Wup    = (const float*)d_in[2];
  const float* m_conv_w = (const float*)d_in[3];
  const float* m_conv_b = (const float*)d_in[4];
  const float* m_Wq     = (const float*)d_in[5];
  const float* m_Wk     = (const float*)d_in[6];
  const float* m_Wv     = (const float*)d_in[7];
  const float* m_Wig    = (const float*)d_in[8];
  const float* m_big    = (const float*)d_in[9];
  const float* m_Wfg    = (const float*)d_in[10];
  const float* m_bfg    = (const float*)d_in[11];
  const float* m_mhln_w = (const float*)d_in[12];
  const float* m_skip   = (const float*)d_in[13];
  const float* m_Wdown  = (const float*)d_in[14];
  const float* s_ln_w   = (const float*)d_in[15];
  const float* s_conv_w = (const float*)d_in[16];
  const float* s_conv_b = (const float*)d_in[17];
  const float* s_Wi     = (const float*)d_in[18];
  const float* s_Wf     = (const float*)d_in[19];
  const float* s_Wz     = (const float*)d_in[20];
  const float* s_Wo     = (const float*)d_in[21];
  const float* s_R      = (const float*)d_in[22];
  const float* s_b      = (const float*)d_in[23];
  const float* s_mhln_w = (const float*)d_in[24];
  const float* s_ffn_ln_w = (const float*)d_in[25];
  const float* s_Wup    = (const float*)d_in[26];
  const float* s_Wdown2 = (const float*)d_in[27];
  const float* post_ln_w = (const float*)d_in[28];
  const float* h_We     = (const float*)d_in[29];
  const float* h_be     = (const float*)d_in[30];
  const float* h_Ws     = (const float*)d_in[31];
  const float* h_bs     = (const float*)d_in[32];
  float* out = (float*)d_out;
  float* ws = (float*)d_ws;

  float* xn = ws + OFF_XN;
  float* up = ws + OFF_UP;
  float* xc = ws + OFF_XC;
  float* hsbuf = ws + OFF_HS;
  float* hb = ws + OFF_H;
  float* x1 = ws + OFF_X1;
  float* wqk_ig = ws + OFF_SM;
  float* wv_ig  = wqk_ig + 8192;
  float* wqk_fg = wqk_ig + 16384;
  float* wv_fg  = wqk_ig + 24576;
  float* igb    = ws + OFF_SM + 32768;
  float* fgb    = igb + 16384;
  float* lfcb   = igb + 32768;
  float* feat   = igb + 49152;

  // ---- block 0: mLSTM ----
  ln1024_kernel<<<4096, 256, 0, stream>>>(x, m_ln_w, xn, 0);
  gemm_kernel<false><<<dim3(32, 32, 1), 256, 0, stream>>>(
      xn, 1024, 0, m_Wup, 4096, 0, nullptr, 0, 0, up, 4096, 0, 4096, 4096, 1024);
  conv_silu_kernel<<<(4096 * 512) / 256, 256, 0, stream>>>(
      up, 4096, m_conv_w, m_conv_b, xc, 2048, 2048);
  wtilde_kernel<<<32, 256, 0, stream>>>(m_Wq, m_Wk, m_Wv, m_Wig, m_Wfg,
                                        wqk_ig, wv_ig, wqk_fg, wv_fg);
  igfg_kernel<<<4096, 256, 0, stream>>>(xc, up, wqk_ig, wv_ig, wqk_fg, wv_fg,
                                        m_big, m_bfg, igb, fgb);
  lfc_kernel<<<16, 1024, 0, stream>>>(fgb, lfcb);
  hv_inplace_kernel<<<8192, 256, 0, stream>>>(up, m_Wv);
  mlstm_attn_kernel<<<dim3(32, 16), 256, 0, stream>>>(
      xc, up, m_Wq, m_Wk, lfcb, igb, hb);
  mhgate_kernel<<<16384, 128, 0, stream>>>(hb, m_mhln_w, m_skip, xc, up);
  gemm_kernel<false><<<dim3(8, 32, 1), 256, 0, stream>>>(
      hb, 2048, 0, m_Wdown, 1024, 0, x, 1024, 0, x1, 1024, 0, 4096, 1024, 2048);

  // ---- block 1: sLSTM ----
  ln1024_kernel<<<4096, 256, 0, stream>>>(x1, s_ln_w, xn, 0);
  conv_silu_kernel<<<(4096 * 256) / 256, 256, 0, stream>>>(
      xn, 1024, s_conv_w, s_conv_b, xc, 1024, 1024);
  float* gi = up;
  float* gf = up + (4l << 20);
  float* gz = up + (8l << 20);
  float* go = up + (12l << 20);
  gemm_kernel<true><<<dim3(2, 32, 4), 256, 0, stream>>>(
      xc, 1024, 256, s_Wi, 256, 65536, nullptr, 0, 0, gi, 1024, 256, 4096, 256, 256);
  gemm_kernel<true><<<dim3(2, 32, 4), 256, 0, stream>>>(
      xc, 1024, 256, s_Wf, 256, 65536, nullptr, 0, 0, gf, 1024, 256, 4096, 256, 256);
  gemm_kernel<true><<<dim3(2, 32, 4), 256, 0, stream>>>(
      xn, 1024, 256, s_Wz, 256, 65536, nullptr, 0, 0, gz, 1024, 256, 4096, 256, 256);
  gemm_kernel<true><<<dim3(2, 32, 4), 256, 0, stream>>>(
      xn, 1024, 256, s_Wo, 256, 65536, nullptr, 0, 0, go, 1024, 256, 4096, 256, 256);
  slstm_scan_kernel<<<16, 1024, 0, stream>>>(gi, gf, gz, go, s_R, s_b, hsbuf);
  mhres_kernel<<<16384, 64, 0, stream>>>(hsbuf, s_mhln_w, x1, hb);
  float* x2 = hb;

  // ---- FFN ----
  ln1024_kernel<<<4096, 256, 0, stream>>>(x2, s_ffn_ln_w, xn, 0);
  float* ffn = up;
  gemm_kernel<false><<<dim3(21, 32, 1), 256, 0, stream>>>(
      xn, 1024, 0, s_Wup, 2688, 0, nullptr, 0, 0, ffn, 2688, 0, 4096, 2688, 1024);
  geglu_kernel<<<(4096 * 1344) / 256, 256, 0, stream>>>(ffn);
  gemm_kernel<false><<<dim3(8, 32, 1), 256, 0, stream>>>(
      ffn, 2688, 0, s_Wdown2, 1024, 0, x2, 1024, 0, x1, 1024, 0, 4096, 1024, 1344);
  float* x3 = x1;

  // ---- post: LN + SELU + mean pool + heads ----
  ln1024_kernel<<<4096, 256, 0, stream>>>(x3, post_ln_w, xn, 1);
  colmean_kernel<<<16, 256, 0, stream>>>(xn, feat);
  head_kernel<<<40, 256, 0, stream>>>(feat, h_We, h_be, h_Ws, h_bs, out);
}